// Round 4
// baseline (226.655 us; speedup 1.0000x reference)
//
#include <hip/hip_runtime.h>

typedef unsigned short u16;
typedef unsigned int u32;
typedef short bf16x8 __attribute__((ext_vector_type(8)));
typedef float f32x4 __attribute__((ext_vector_type(4)));

#define AS1 __attribute__((address_space(1)))
#define AS3 __attribute__((address_space(3)))

#define NTOK 4096
#define HDIM 512
#define FDIM 2048
#define NEXP 8
#define NASSIGN (NTOK * 2)
#define NPAD2 (NASSIGN + NEXP * 256)  // 10240: 256-padded rows upper bound
#define RBMAX 128

__device__ __forceinline__ void g2l16(const void* g, void* l) {
  __builtin_amdgcn_global_load_lds((const AS1 u32*)g, (AS3 u32*)l, 16, 0, 0);
}
__device__ __forceinline__ u16 f2bf(float f) {
  u32 u = __float_as_uint(f);
  u = (u + 0x7FFFu + ((u >> 16) & 1u)) >> 16;
  return (u16)u;
}
__device__ __forceinline__ float bf2f(u16 h) { return __uint_as_float(((u32)h) << 16); }

#define WAITV4() asm volatile("s_waitcnt vmcnt(4)" ::: "memory")
#define WAITV0() asm volatile("s_waitcnt vmcnt(0)" ::: "memory")
#define BAR() __builtin_amdgcn_s_barrier()
#define VMBAR() do { WAITV0(); BAR(); } while (0)

// ---------------- cvtall + wreff fused (cvt blocks are LDS-free, full occupancy) ----------------
__global__ __launch_bounds__(256) void cvtall_kernel(
    const float* __restrict__ x, const float* __restrict__ Wi, const float* __restrict__ Wo,
    const float* __restrict__ Wg, const float* __restrict__ Wu, const float* __restrict__ Wd,
    const float* __restrict__ Wr,
    u16* __restrict__ xb, u16* __restrict__ Wib, u16* __restrict__ Wob,
    u16* __restrict__ Wgb, u16* __restrict__ Wub, u16* __restrict__ Wdb,
    double* __restrict__ wre) {
  const int b = blockIdx.x, tid = threadIdx.x;
  if (b < 6784) {
    const int gid = b * 256 + tid;
    const int S = 6784 * 256;
#pragma unroll
    for (int k = 0; k < 4; ++k) {
      const int i = gid + k * S;
      const float* s; u16* d; int o;
      if (i < 524288) { s = x; d = xb; o = i; }
      else if (i < 589824) { s = Wi; d = Wib; o = i - 524288; }
      else if (i < 655360) { s = Wo; d = Wob; o = i - 589824; }
      else if (i < 2752512) { s = Wg; d = Wgb; o = i - 655360; }
      else if (i < 4849664) { s = Wu; d = Wub; o = i - 2752512; }
      else { s = Wd; d = Wdb; o = i - 4849664; }
      const float4 v = ((const float4*)s)[o];
      ushort4 t; t.x = f2bf(v.x); t.y = f2bf(v.y); t.z = f2bf(v.z); t.w = f2bf(v.w);
      ((ushort4*)d)[o] = t;
    }
  } else {
    // Wr_eff = W_router @ W_in in fp64 (exact routing)
    const int t = (b - 6784) * 256 + tid;  // e*512+k
    const int e = t >> 9, k = t & 511;
    const float* wr = Wr + e * HDIM;
    double a = 0.0;
    for (int j = 0; j < HDIM; j += 8) {
#pragma unroll
      for (int u = 0; u < 8; ++u) a += (double)wr[j + u] * (double)Wi[(j + u) * HDIM + k];
    }
    wre[t] = a;
  }
}

// ---------------- router: logits = x @ Wr_eff^T (fp64), softmax, top-2 ----------------
__global__ __launch_bounds__(128) void router_kernel(
    const float* __restrict__ x, const double* __restrict__ wre,
    int* __restrict__ idx, float* __restrict__ wts) {
  __shared__ double lw[NEXP * HDIM];  // 32 KB
  for (int i = threadIdx.x; i < NEXP * HDIM; i += 128) lw[i] = wre[i];
  __syncthreads();
  const int n = blockIdx.x * 128 + threadIdx.x;
  const float* xr = x + (size_t)n * HDIM;
  double acc[NEXP] = {};
  for (int k4 = 0; k4 < HDIM / 4; ++k4) {
    const float4 xv = ((const float4*)xr)[k4];
    const float xc[4] = {xv.x, xv.y, xv.z, xv.w};
#pragma unroll
    for (int c = 0; c < 4; ++c) {
      const double xd = (double)xc[c];
#pragma unroll
      for (int e = 0; e < NEXP; ++e) acc[e] += xd * lw[e * HDIM + k4 * 4 + c];
    }
  }
  double mx = acc[0];
#pragma unroll
  for (int e = 1; e < NEXP; ++e) mx = acc[e] > mx ? acc[e] : mx;
  double p[NEXP], se = 0.0;
#pragma unroll
  for (int e = 0; e < NEXP; ++e) { p[e] = exp(acc[e] - mx); se += p[e]; }
  const double inv = 1.0 / se;
#pragma unroll
  for (int e = 0; e < NEXP; ++e) p[e] *= inv;
  int i0 = 0; double b0 = p[0];
#pragma unroll
  for (int e = 1; e < NEXP; ++e) if (p[e] > b0) { b0 = p[e]; i0 = e; }
  int i1 = -1; double b1 = -1.0;
#pragma unroll
  for (int e = 0; e < NEXP; ++e) if (e != i0 && p[e] > b1) { b1 = p[e]; i1 = e; }
  const double e0 = exp(b0), e1 = exp(b1);  // softmax OF the top-2 probabilities
  idx[2 * n] = i0; idx[2 * n + 1] = i1;
  wts[2 * n] = (float)(e0 / (e0 + e1));
  wts[2 * n + 1] = (float)(e1 / (e0 + e1));
}

// ---------------- gather lists + dual rowblock schedules (256-pad layout) ----------------
__global__ void assign_kernel(const int* __restrict__ idx, int* __restrict__ tok,
                              int* __restrict__ pos, int* __restrict__ rbe2,
                              int* __restrict__ rbp2, int* __restrict__ rbe1,
                              int* __restrict__ rbp1, int* __restrict__ nrb) {
  __shared__ int cnt[NEXP], cur[NEXP];
  const int tid = threadIdx.x;
  if (tid < NEXP) cnt[tid] = 0;
  __syncthreads();
  for (int a = tid; a < NASSIGN; a += 256) atomicAdd(&cnt[idx[a]], 1);
  __syncthreads();
  if (tid == 0) {
    int o = 0, n2 = 0, n1 = 0;
    for (int e = 0; e < NEXP; ++e) {
      cur[e] = o;
      const int nb2 = (cnt[e] + 255) >> 8;
      const int nb1 = (cnt[e] + 127) >> 7;
      for (int i = 0; i < nb2; ++i) { rbe2[n2] = e; rbp2[n2] = o + i * 256; ++n2; }
      for (int i = 0; i < nb1; ++i) { rbe1[n1] = e; rbp1[n1] = o + i * 128; ++n1; }
      o += nb2 * 256;
    }
    nrb[0] = n2; nrb[1] = n1;
  }
  __syncthreads();
  for (int p = tid; p < NPAD2; p += 256) tok[p] = 0;  // pad rows -> token 0 (never read back)
  __syncthreads();
  for (int a = tid; a < NASSIGN; a += 256) {
    const int e = idx[a];
    const int q = atomicAdd(&cur[e], 1);
    tok[q] = a >> 1;
    pos[a] = q;
  }
}

// ---------------- 128x128 BT GEMM body (2-phase dbuf, BK=64 swizzle) — proj GEMMs ----------------
template <int SB, int NT>
__device__ __forceinline__ void gemm128_body(
    const u16* __restrict__ A, const u16* __restrict__ B, void* __restrict__ C,
    int m0, int n0, int N, int K, u16* sm, int tid) {
  u16 *lA0 = sm, *lA1 = sm + 8192, *lB0 = sm + 16384, *lB1 = sm + 24576;
  const int w = tid >> 6, l = tid & 63;
  const int wm = (w >> 2) * 64, wn = (w & 3) * 32;
  const int lm = l & 15, lk = (l >> 4) * 8, xr = (l & 7) << 3;
  const int sr = l >> 3, sc = ((l & 7) ^ sr) * 8;
  const u16* As = A + (size_t)(m0 + w * 8 + sr) * K + sc;
  const u16* Bs = B + (size_t)(n0 + w * 8 + sr) * K + sc;
  f32x4 acc[4][2] = {};
  auto STG = [&](u16* dA, u16* dB, int kt) {
    g2l16(As + kt, dA + w * 512);
    g2l16(As + (size_t)64 * K + kt, dA + 4096 + w * 512);
    g2l16(Bs + kt, dB + w * 512);
    g2l16(Bs + (size_t)64 * K + kt, dB + 4096 + w * 512);
  };
  auto CMP = [&](const u16* a_, const u16* b_) {
#pragma unroll
    for (int kk = 0; kk < 2; ++kk) {
      const int ko = (kk * 32 + lk) ^ xr;
      bf16x8 af[4], bf[2];
#pragma unroll
      for (int i = 0; i < 4; ++i) af[i] = *(const bf16x8*)(a_ + (wm + i * 16 + lm) * 64 + ko);
#pragma unroll
      for (int j = 0; j < 2; ++j) bf[j] = *(const bf16x8*)(b_ + (wn + j * 16 + lm) * 64 + ko);
#pragma unroll
      for (int i = 0; i < 4; ++i)
#pragma unroll
        for (int j = 0; j < 2; ++j)
          acc[i][j] = __builtin_amdgcn_mfma_f32_16x16x32_bf16(af[i], bf[j], acc[i][j], 0, 0, 0);
    }
  };
  STG(lA0, lB0, 0);
  VMBAR();
  for (int t = 0; t < NT; t += 2) {
    if (t + 1 < NT) STG(lA1, lB1, (t + 1) * 64);
    CMP(lA0, lB0);
    VMBAR();
    if (t + 2 < NT) STG(lA0, lB0, (t + 2) * 64);
    CMP(lA1, lB1);
    VMBAR();
  }
  const int cr = (l >> 4) * 4, cc = lm;
#pragma unroll
  for (int i = 0; i < 4; ++i)
#pragma unroll
    for (int j = 0; j < 2; ++j)
#pragma unroll
      for (int r = 0; r < 4; ++r) {
        const size_t o = (size_t)(m0 + wm + i * 16 + cr + r) * N + n0 + wn + j * 16 + cc;
        if (SB) ((u16*)C)[o] = f2bf(acc[i][j][r]);
        else ((float*)C)[o] = acc[i][j][r];
      }
}

__global__ __launch_bounds__(512, 2) void ingemm_kernel(
    const u16* __restrict__ xb, const u16* __restrict__ Wib, u16* __restrict__ hb) {
  __shared__ __align__(16) u16 sm[32768];  // 64 KB
  gemm128_body<1, 8>(xb, Wib, hb, blockIdx.y * 128, blockIdx.x * 128, HDIM, HDIM, sm, threadIdx.x);
}

__global__ __launch_bounds__(512, 2) void outgemm_kernel(
    const u16* __restrict__ cb, const u16* __restrict__ Wob, float* __restrict__ out) {
  __shared__ __align__(16) u16 sm[32768];  // 64 KB
  gemm128_body<0, 8>(cb, Wob, out, blockIdx.y * 128, blockIdx.x * 128, HDIM, HDIM, sm, threadIdx.x);
}

// ---- gateup: 256 rows x (128 gate + 128 up), 8 waves of 128x(32+32), BK=32, 3-stage ----
__global__ __launch_bounds__(512, 2) void gateup_kernel(
    const u16* __restrict__ hb, const u16* __restrict__ Wg, const u16* __restrict__ Wu,
    u16* __restrict__ act, const int* __restrict__ tok, const int* __restrict__ rbe2,
    const int* __restrict__ rbp2, const int* __restrict__ nrb) {
  const int rb = blockIdx.y;
  if (rb >= nrb[0]) return;
  __shared__ __align__(16) u16 sm[49152];  // 96 KB: 3 stages x (A 8192 | G 4096 | U 4096 elems)
  const int e = rbe2[rb], p0 = rbp2[rb], n0 = blockIdx.x * 128;
  const int tid = threadIdx.x, w = tid >> 6, l = tid & 63;
  const int lrow = l >> 2;                       // 0..15 within 16-row stage group
  const int scb = ((l & 3) ^ ((lrow >> 1) & 3)) * 8;  // swizzled source col (elems)
  const int rm = (w >> 2) * 128, cg = (w & 3) * 32;
  const int lm = l & 15;
  const int koe = ((l >> 4) ^ ((l >> 1) & 3)) << 3;   // swizzled frag col (elems)
  const u16* As0 = hb + (size_t)tok[p0 + (w * 2 + 0) * 16 + lrow] * HDIM + scb;
  const u16* As1 = hb + (size_t)tok[p0 + (w * 2 + 1) * 16 + lrow] * HDIM + scb;
  const u16* Gs = Wg + (size_t)e * FDIM * HDIM + (size_t)(n0 + w * 16 + lrow) * HDIM + scb;
  const u16* Us = Wu + (size_t)e * FDIM * HDIM + (size_t)(n0 + w * 16 + lrow) * HDIM + scb;
  f32x4 ag[8][2] = {}, au[8][2] = {};
  auto STG = [&](int b, int t) {  // 4 vmem instrs / wave
    u16* base = sm + b * 16384;
    const int kt = t * 32;
    g2l16(As0 + kt, base + (w * 2 + 0) * 512);
    g2l16(As1 + kt, base + (w * 2 + 1) * 512);
    g2l16(Gs + kt, base + 8192 + w * 512);
    g2l16(Us + kt, base + 12288 + w * 512);
  };
  auto CMP = [&](int b) {  // 12 ds_read_b128 + 32 MFMA
    const u16* a_ = sm + b * 16384;
    const u16* g_ = a_ + 8192;
    const u16* u_ = a_ + 12288;
    bf16x8 gf[2], uf[2];
#pragma unroll
    for (int j = 0; j < 2; ++j) {
      gf[j] = *(const bf16x8*)(g_ + (cg + j * 16 + lm) * 32 + koe);
      uf[j] = *(const bf16x8*)(u_ + (cg + j * 16 + lm) * 32 + koe);
    }
#pragma unroll
    for (int i = 0; i < 8; ++i) {
      const bf16x8 af = *(const bf16x8*)(a_ + (rm + i * 16 + lm) * 32 + koe);
#pragma unroll
      for (int j = 0; j < 2; ++j) {
        ag[i][j] = __builtin_amdgcn_mfma_f32_16x16x32_bf16(af, gf[j], ag[i][j], 0, 0, 0);
        au[i][j] = __builtin_amdgcn_mfma_f32_16x16x32_bf16(af, uf[j], au[i][j], 0, 0, 0);
      }
    }
  };
  STG(0, 0); STG(1, 1);
  WAITV4(); BAR();
#pragma unroll
  for (int t = 0; t < 16; ++t) {
    if (t + 2 < 16) STG((t + 2) % 3, t + 2);
    CMP(t % 3);
    if (t + 2 < 16) { WAITV4(); } else { WAITV0(); }
    BAR();
  }
  const int cr = (l >> 4) * 4, cc = lm;
#pragma unroll
  for (int i = 0; i < 8; ++i)
#pragma unroll
    for (int j = 0; j < 2; ++j)
#pragma unroll
      for (int r = 0; r < 4; ++r) {
        const float g = ag[i][j][r], u = au[i][j][r];
        const float s = g / (1.0f + __expf(-g));
        act[(size_t)(p0 + rm + i * 16 + cr + r) * FDIM + n0 + cg + j * 16 + cc] = f2bf(s * u);
      }
}

// ---- down: 128x128 tile, 4 waves of 64x64, BK=32, 3-stage 48KB -> 3 blocks/CU ----
__global__ __launch_bounds__(256, 3) void down_kernel(
    const u16* __restrict__ act, const u16* __restrict__ Wd, u16* __restrict__ dwn,
    const int* __restrict__ rbe1, const int* __restrict__ rbp1, const int* __restrict__ nrb) {
  const int rb = blockIdx.y;
  if (rb >= nrb[1]) return;
  __shared__ __align__(16) u16 sm[24576];  // 48 KB: 3 stages x (A 4096 | B 4096 elems)
  const int e = rbe1[rb], p0 = rbp1[rb], n0 = blockIdx.x * 128;
  const int tid = threadIdx.x, w = tid >> 6, l = tid & 63;
  const int lrow = l >> 2;
  const int scb = ((l & 3) ^ ((lrow >> 1) & 3)) * 8;
  const int wm = (w >> 1) * 64, wn = (w & 1) * 64;
  const int lm = l & 15;
  const int koe = ((l >> 4) ^ ((l >> 1) & 3)) << 3;
  const u16* As0 = act + (size_t)(p0 + (w * 2 + 0) * 16 + lrow) * FDIM + scb;
  const u16* As1 = act + (size_t)(p0 + (w * 2 + 1) * 16 + lrow) * FDIM + scb;
  const u16* Bs0 = Wd + (size_t)e * HDIM * FDIM + (size_t)(n0 + (w * 2 + 0) * 16 + lrow) * FDIM + scb;
  const u16* Bs1 = Wd + (size_t)e * HDIM * FDIM + (size_t)(n0 + (w * 2 + 1) * 16 + lrow) * FDIM + scb;
  f32x4 acc[4][4] = {};
  auto STG = [&](int b, int t) {  // 4 vmem instrs / wave
    u16* base = sm + b * 8192;
    const int kt = t * 32;
    g2l16(As0 + kt, base + (w * 2 + 0) * 512);
    g2l16(As1 + kt, base + (w * 2 + 1) * 512);
    g2l16(Bs0 + kt, base + 4096 + (w * 2 + 0) * 512);
    g2l16(Bs1 + kt, base + 4096 + (w * 2 + 1) * 512);
  };
  auto CMP = [&](int b) {  // 8 ds_read_b128 + 16 MFMA
    const u16* a_ = sm + b * 8192;
    const u16* b_ = a_ + 4096;
    bf16x8 bf[4];
#pragma unroll
    for (int j = 0; j < 4; ++j) bf[j] = *(const bf16x8*)(b_ + (wn + j * 16 + lm) * 32 + koe);
#pragma unroll
    for (int i = 0; i < 4; ++i) {
      const bf16x8 af = *(const bf16x8*)(a_ + (wm + i * 16 + lm) * 32 + koe);
#pragma unroll
      for (int j = 0; j < 4; ++j)
        acc[i][j] = __builtin_amdgcn_mfma_f32_16x16x32_bf16(af, bf[j], acc[i][j], 0, 0, 0);
    }
  };
  STG(0, 0); STG(1, 1);
  WAITV4(); BAR();
#pragma unroll
  for (int t = 0; t < 64; ++t) {
    if (t + 2 < 64) STG((t + 2) % 3, t + 2);
    CMP(t % 3);
    if (t + 2 < 64) { WAITV4(); } else { WAITV0(); }
    BAR();
  }
  const int cr = (l >> 4) * 4, cc = lm;
#pragma unroll
  for (int i = 0; i < 4; ++i)
#pragma unroll
    for (int j = 0; j < 4; ++j)
#pragma unroll
      for (int r = 0; r < 4; ++r)
        dwn[(size_t)(p0 + wm + i * 16 + cr + r) * HDIM + n0 + wn + j * 16 + cc] = f2bf(acc[i][j][r]);
}

// ---------------- combine: c[n] = w0*down[pos0] + w1*down[pos1] (bf16 in/out) ----------------
__global__ void combine_kernel(const u16* __restrict__ dwn, const int* __restrict__ pos,
                               const float* __restrict__ wts, u16* __restrict__ cb) {
  const int n = blockIdx.x, t = threadIdx.x;  // 128 threads x 4 elems
  const int p0 = pos[2 * n], p1 = pos[2 * n + 1];
  const float w0 = wts[2 * n], w1 = wts[2 * n + 1];
  const ushort4 a = ((const ushort4*)(dwn + (size_t)p0 * HDIM))[t];
  const ushort4 b = ((const ushort4*)(dwn + (size_t)p1 * HDIM))[t];
  ushort4 o;
  o.x = f2bf(w0 * bf2f(a.x) + w1 * bf2f(b.x));
  o.y = f2bf(w0 * bf2f(a.y) + w1 * bf2f(b.y));
  o.z = f2bf(w0 * bf2f(a.z) + w1 * bf2f(b.z));
  o.w = f2bf(w0 * bf2f(a.w) + w1 * bf2f(b.w));
  ((ushort4*)(cb + (size_t)n * HDIM))[t] = o;
}

extern "C" void kernel_launch(void* const* d_in, const int* in_sizes, int n_in,
                              void* d_out, int out_size, void* d_ws, size_t ws_size,
                              hipStream_t stream) {
  const float* x  = (const float*)d_in[0];
  const float* Wi = (const float*)d_in[1];
  const float* Wr = (const float*)d_in[2];
  const float* Wg = (const float*)d_in[3];
  const float* Wu = (const float*)d_in[4];
  const float* Wd = (const float*)d_in[5];
  const float* Wo = (const float*)d_in[6];
  float* out = (float*)d_out;

  char* ws = (char*)d_ws;
  size_t off = 0;
  auto alloc = [&](size_t bytes) -> void* {
    off = (off + 255) & ~(size_t)255;
    void* p = ws + off;
    off += bytes;
    return p;
  };
  u16* xb  = (u16*)alloc((size_t)NTOK * HDIM * 2);
  u16* hb  = (u16*)alloc((size_t)NTOK * HDIM * 2);
  u16* cb  = (u16*)alloc((size_t)NTOK * HDIM * 2);
  u16* Wib = (u16*)alloc((size_t)HDIM * HDIM * 2);
  u16* Wob = (u16*)alloc((size_t)HDIM * HDIM * 2);
  u16* Wgb = (u16*)alloc((size_t)NEXP * FDIM * HDIM * 2);
  u16* Wub = (u16*)alloc((size_t)NEXP * FDIM * HDIM * 2);
  u16* Wdb = (u16*)alloc((size_t)NEXP * HDIM * FDIM * 2);
  u16* actb = (u16*)alloc((size_t)NPAD2 * FDIM * 2);
  u16* dwn = (u16*)alloc((size_t)NPAD2 * HDIM * 2);
  double* wre = (double*)alloc((size_t)NEXP * HDIM * 8);
  int* idx = (int*)alloc((size_t)NASSIGN * 4);
  float* wts = (float*)alloc((size_t)NASSIGN * 4);
  int* tok = (int*)alloc((size_t)NPAD2 * 4);
  int* pos = (int*)alloc((size_t)NASSIGN * 4);
  int* rbe2 = (int*)alloc((size_t)RBMAX * 4);
  int* rbp2 = (int*)alloc((size_t)RBMAX * 4);
  int* rbe1 = (int*)alloc((size_t)RBMAX * 4);
  int* rbp1 = (int*)alloc((size_t)RBMAX * 4);
  int* nrb = (int*)alloc(256);

  cvtall_kernel<<<6800, 256, 0, stream>>>(x, Wi, Wo, Wg, Wu, Wd, Wr,
                                          xb, Wib, Wob, Wgb, Wub, Wdb, wre);
  router_kernel<<<32, 128, 0, stream>>>(x, wre, idx, wts);
  assign_kernel<<<1, 256, 0, stream>>>(idx, tok, pos, rbe2, rbp2, rbe1, rbp1, nrb);
  ingemm_kernel<<<dim3(4, 32), 512, 0, stream>>>(xb, Wib, hb);
  gateup_kernel<<<dim3(16, 40), 512, 0, stream>>>(hb, Wgb, Wub, actb, tok, rbe2, rbp2, nrb);
  down_kernel<<<dim3(4, 72), 256, 0, stream>>>(actb, Wdb, dwn, rbe1, rbp1, nrb);
  combine_kernel<<<NTOK, 128, 0, stream>>>(dwn, pos, wts, cb);
  outgemm_kernel<<<dim3(4, 32), 512, 0, stream>>>(cb, Wob, out);
}

// Round 5
// 224.694 us; speedup vs baseline: 1.0087x; 1.0087x over previous
//
#include <hip/hip_runtime.h>

typedef unsigned short u16;
typedef unsigned int u32;
typedef short bf16x8 __attribute__((ext_vector_type(8)));
typedef float f32x4 __attribute__((ext_vector_type(4)));

#define AS1 __attribute__((address_space(1)))
#define AS3 __attribute__((address_space(3)))

#define NTOK 4096
#define HDIM 512
#define FDIM 2048
#define NEXP 8
#define NASSIGN (NTOK * 2)
#define NPAD2 (NASSIGN + NEXP * 256)  // 10240
#define RBMAX 128

__device__ __forceinline__ void g2l16(const void* g, void* l) {
  __builtin_amdgcn_global_load_lds((const AS1 u32*)g, (AS3 u32*)l, 16, 0, 0);
}
__device__ __forceinline__ u16 f2bf(float f) {
  u32 u = __float_as_uint(f);
  u = (u + 0x7FFFu + ((u >> 16) & 1u)) >> 16;
  return (u16)u;
}
__device__ __forceinline__ float bf2f(u16 h) { return __uint_as_float(((u32)h) << 16); }

#define WAITV0() asm volatile("s_waitcnt vmcnt(0)" ::: "memory")
#define BAR() __builtin_amdgcn_s_barrier()
#define SCB() __builtin_amdgcn_sched_barrier(0)
#define PRIO1() __builtin_amdgcn_s_setprio(1)
#define PRIO0() __builtin_amdgcn_s_setprio(0)
#define VMBAR() do { WAITV0(); BAR(); } while (0)

// ---------------- cvtall: block-contiguous chunks, batched loads + wreff (fp64) ----------------
// float4 boundaries (all multiples of 1024): x 524288 | Wi 589824 | Wo 655360 |
// Wg 2752512 | Wu 4849664 | Wd 6946816  -> 6784 cvt blocks of 1024 float4
__global__ __launch_bounds__(256) void cvtall_kernel(
    const float* __restrict__ x, const float* __restrict__ Wi, const float* __restrict__ Wo,
    const float* __restrict__ Wg, const float* __restrict__ Wu, const float* __restrict__ Wd,
    const float* __restrict__ Wr,
    u16* __restrict__ xb, u16* __restrict__ Wib, u16* __restrict__ Wob,
    u16* __restrict__ Wgb, u16* __restrict__ Wub, u16* __restrict__ Wdb,
    double* __restrict__ wre) {
  const int b = blockIdx.x, tid = threadIdx.x;
  if (b < 6784) {
    const int b4 = b * 1024;  // block-uniform segment select
    const float* s; u16* d; int o;
    if (b4 < 524288) { s = x; d = xb; o = b4; }
    else if (b4 < 589824) { s = Wi; d = Wib; o = b4 - 524288; }
    else if (b4 < 655360) { s = Wo; d = Wob; o = b4 - 589824; }
    else if (b4 < 2752512) { s = Wg; d = Wgb; o = b4 - 655360; }
    else if (b4 < 4849664) { s = Wu; d = Wub; o = b4 - 2752512; }
    else { s = Wd; d = Wdb; o = b4 - 4849664; }
    const int oo = o + tid;
    const float4 v0 = ((const float4*)s)[oo];
    const float4 v1 = ((const float4*)s)[oo + 256];
    const float4 v2 = ((const float4*)s)[oo + 512];
    const float4 v3 = ((const float4*)s)[oo + 768];
    ushort4 t0, t1, t2, t3;
    t0.x = f2bf(v0.x); t0.y = f2bf(v0.y); t0.z = f2bf(v0.z); t0.w = f2bf(v0.w);
    t1.x = f2bf(v1.x); t1.y = f2bf(v1.y); t1.z = f2bf(v1.z); t1.w = f2bf(v1.w);
    t2.x = f2bf(v2.x); t2.y = f2bf(v2.y); t2.z = f2bf(v2.z); t2.w = f2bf(v2.w);
    t3.x = f2bf(v3.x); t3.y = f2bf(v3.y); t3.z = f2bf(v3.z); t3.w = f2bf(v3.w);
    ((ushort4*)d)[oo] = t0;
    ((ushort4*)d)[oo + 256] = t1;
    ((ushort4*)d)[oo + 512] = t2;
    ((ushort4*)d)[oo + 768] = t3;
  } else {
    // Wr_eff = W_router @ W_in in fp64 (exact routing), 4-way ILP
    const int t = (b - 6784) * 256 + tid;  // e*512+k
    const int e = t >> 9, k = t & 511;
    const float* wr = Wr + e * HDIM;
    double a0 = 0.0, a1 = 0.0, a2 = 0.0, a3 = 0.0;
    for (int j = 0; j < HDIM; j += 4) {
      a0 += (double)wr[j + 0] * (double)Wi[(j + 0) * HDIM + k];
      a1 += (double)wr[j + 1] * (double)Wi[(j + 1) * HDIM + k];
      a2 += (double)wr[j + 2] * (double)Wi[(j + 2) * HDIM + k];
      a3 += (double)wr[j + 3] * (double)Wi[(j + 3) * HDIM + k];
    }
    wre[t] = (a0 + a1) + (a2 + a3);
  }
}

// ---------------- router: logits = x @ Wr_eff^T (fp64), softmax, top-2 ----------------
__global__ __launch_bounds__(128) void router_kernel(
    const float* __restrict__ x, const double* __restrict__ wre,
    int* __restrict__ idx, float* __restrict__ wts) {
  __shared__ double lw[NEXP * HDIM];  // 32 KB
  for (int i = threadIdx.x; i < NEXP * HDIM; i += 128) lw[i] = wre[i];
  __syncthreads();
  const int n = blockIdx.x * 128 + threadIdx.x;
  const float* xr = x + (size_t)n * HDIM;
  double acc[NEXP] = {};
  for (int k4 = 0; k4 < HDIM / 4; ++k4) {
    const float4 xv = ((const float4*)xr)[k4];
    const float xc[4] = {xv.x, xv.y, xv.z, xv.w};
#pragma unroll
    for (int c = 0; c < 4; ++c) {
      const double xd = (double)xc[c];
#pragma unroll
      for (int e = 0; e < NEXP; ++e) acc[e] += xd * lw[e * HDIM + k4 * 4 + c];
    }
  }
  double mx = acc[0];
#pragma unroll
  for (int e = 1; e < NEXP; ++e) mx = acc[e] > mx ? acc[e] : mx;
  double p[NEXP], se = 0.0;
#pragma unroll
  for (int e = 0; e < NEXP; ++e) { p[e] = exp(acc[e] - mx); se += p[e]; }
  const double inv = 1.0 / se;
#pragma unroll
  for (int e = 0; e < NEXP; ++e) p[e] *= inv;
  int i0 = 0; double b0 = p[0];
#pragma unroll
  for (int e = 1; e < NEXP; ++e) if (p[e] > b0) { b0 = p[e]; i0 = e; }
  int i1 = -1; double b1 = -1.0;
#pragma unroll
  for (int e = 0; e < NEXP; ++e) if (e != i0 && p[e] > b1) { b1 = p[e]; i1 = e; }
  const double e0 = exp(b0), e1 = exp(b1);  // softmax OF the top-2 probabilities
  idx[2 * n] = i0; idx[2 * n + 1] = i1;
  wts[2 * n] = (float)(e0 / (e0 + e1));
  wts[2 * n + 1] = (float)(e1 / (e0 + e1));
}

// ---------------- gather lists + dual rowblock schedules (256-pad layout) ----------------
__global__ void assign_kernel(const int* __restrict__ idx, int* __restrict__ tok,
                              int* __restrict__ pos, int* __restrict__ rbe2,
                              int* __restrict__ rbp2, int* __restrict__ rbe1,
                              int* __restrict__ rbp1, int* __restrict__ nrb) {
  __shared__ int cnt[NEXP], cur[NEXP];
  const int tid = threadIdx.x;
  if (tid < NEXP) cnt[tid] = 0;
  __syncthreads();
  for (int a = tid; a < NASSIGN; a += 256) atomicAdd(&cnt[idx[a]], 1);
  __syncthreads();
  if (tid == 0) {
    int o = 0, n2 = 0, n1 = 0;
    for (int e = 0; e < NEXP; ++e) {
      cur[e] = o;
      const int nb2 = (cnt[e] + 255) >> 8;
      const int nb1 = (cnt[e] + 127) >> 7;
      for (int i = 0; i < nb2; ++i) { rbe2[n2] = e; rbp2[n2] = o + i * 256; ++n2; }
      for (int i = 0; i < nb1; ++i) { rbe1[n1] = e; rbp1[n1] = o + i * 128; ++n1; }
      o += nb2 * 256;
    }
    nrb[0] = n2; nrb[1] = n1;
  }
  __syncthreads();
  for (int p = tid; p < NPAD2; p += 256) tok[p] = 0;  // pad rows -> token 0 (never read back)
  __syncthreads();
  for (int a = tid; a < NASSIGN; a += 256) {
    const int e = idx[a];
    const int q = atomicAdd(&cur[e], 1);
    tok[q] = a >> 1;
    pos[a] = q;
  }
}

// ---------------- 128x128 BT GEMM body (2-phase dbuf, swizzled) — proj GEMMs ----------------
template <int SB, int NT>
__device__ __forceinline__ void gemm128_body(
    const u16* __restrict__ A, const u16* __restrict__ B, void* __restrict__ C,
    int m0, int n0, int N, int K, u16* sm, int tid) {
  u16 *lA0 = sm, *lA1 = sm + 8192, *lB0 = sm + 16384, *lB1 = sm + 24576;
  const int w = tid >> 6, l = tid & 63;
  const int wm = (w >> 2) * 64, wn = (w & 3) * 32;
  const int lm = l & 15, lk = (l >> 4) * 8, xr = (l & 7) << 3;
  const int sr = l >> 3, sc = ((l & 7) ^ sr) * 8;
  const u16* As = A + (size_t)(m0 + w * 8 + sr) * K + sc;
  const u16* Bs = B + (size_t)(n0 + w * 8 + sr) * K + sc;
  f32x4 acc[4][2] = {};
  auto STG = [&](u16* dA, u16* dB, int kt) {
    g2l16(As + kt, dA + w * 512);
    g2l16(As + (size_t)64 * K + kt, dA + 4096 + w * 512);
    g2l16(Bs + kt, dB + w * 512);
    g2l16(Bs + (size_t)64 * K + kt, dB + 4096 + w * 512);
  };
  auto CMP = [&](const u16* a_, const u16* b_) {
#pragma unroll
    for (int kk = 0; kk < 2; ++kk) {
      const int ko = (kk * 32 + lk) ^ xr;
      bf16x8 af[4], bf[2];
#pragma unroll
      for (int i = 0; i < 4; ++i) af[i] = *(const bf16x8*)(a_ + (wm + i * 16 + lm) * 64 + ko);
#pragma unroll
      for (int j = 0; j < 2; ++j) bf[j] = *(const bf16x8*)(b_ + (wn + j * 16 + lm) * 64 + ko);
#pragma unroll
      for (int i = 0; i < 4; ++i)
#pragma unroll
        for (int j = 0; j < 2; ++j)
          acc[i][j] = __builtin_amdgcn_mfma_f32_16x16x32_bf16(af[i], bf[j], acc[i][j], 0, 0, 0);
    }
  };
  STG(lA0, lB0, 0);
  VMBAR();
  for (int t = 0; t < NT; t += 2) {
    if (t + 1 < NT) STG(lA1, lB1, (t + 1) * 64);
    CMP(lA0, lB0);
    VMBAR();
    if (t + 2 < NT) STG(lA0, lB0, (t + 2) * 64);
    CMP(lA1, lB1);
    VMBAR();
  }
  const int cr = (l >> 4) * 4, cc = lm;
#pragma unroll
  for (int i = 0; i < 4; ++i)
#pragma unroll
    for (int j = 0; j < 2; ++j)
#pragma unroll
      for (int r = 0; r < 4; ++r) {
        const size_t o = (size_t)(m0 + wm + i * 16 + cr + r) * N + n0 + wn + j * 16 + cc;
        if (SB) ((u16*)C)[o] = f2bf(acc[i][j][r]);
        else ((float*)C)[o] = acc[i][j][r];
      }
}

__global__ __launch_bounds__(512, 2) void ingemm_kernel(
    const u16* __restrict__ xb, const u16* __restrict__ Wib, u16* __restrict__ hb) {
  __shared__ __align__(16) u16 sm[32768];  // 64 KB
  gemm128_body<1, 8>(xb, Wib, hb, blockIdx.y * 128, blockIdx.x * 128, HDIM, HDIM, sm, threadIdx.x);
}

__global__ __launch_bounds__(512, 2) void outgemm_kernel(
    const u16* __restrict__ cb, const u16* __restrict__ Wob, float* __restrict__ out) {
  __shared__ __align__(16) u16 sm[32768];  // 64 KB
  gemm128_body<0, 8>(cb, Wob, out, blockIdx.y * 128, blockIdx.x * 128, HDIM, HDIM, sm, threadIdx.x);
}

// ---- gateup: 256 rows x (128G+128U), 8 waves of 64x(64+64), BK=64, 2-stage 128 KB,
// ---- 4 phases/K-tile: {ds_read || stage-issue || 16-MFMA cluster}, vmcnt(0) once per tile ----
__global__ __launch_bounds__(512, 2) void gateup_kernel(
    const u16* __restrict__ hb, const u16* __restrict__ Wg, const u16* __restrict__ Wu,
    u16* __restrict__ act, const int* __restrict__ tok, const int* __restrict__ rbe2,
    const int* __restrict__ rbp2, const int* __restrict__ nrb) {
  const int rb = blockIdx.y;
  if (rb >= nrb[0]) return;
  __shared__ __align__(16) u16 sm[65536];  // 128 KB: 2 x (A[256][64] | G[128][64] | U[128][64])
  const int e = rbe2[rb], p0 = rbp2[rb], n0 = blockIdx.x * 128;
  const int tid = threadIdx.x, w = tid >> 6, l = tid & 63;
  const int wr = w >> 1, wc = w & 1;  // wave: rows wr*64, cols wc*64 (of G and of U)
  const int lm = l & 15, lk = (l >> 4) * 8, xr = (l & 7) * 8;
  const int sr = l >> 3, sc = ((l & 7) ^ sr) * 8;  // pre-swizzled source col
  const int ko0 = lk ^ xr, ko1 = (32 + lk) ^ xr;
  const u16* Asrc[4];
#pragma unroll
  for (int c = 0; c < 4; ++c)
    Asrc[c] = hb + (size_t)tok[p0 + c * 64 + w * 8 + sr] * HDIM + sc;
  const u16 *Gsrc[2], *Usrc[2];
#pragma unroll
  for (int c = 0; c < 2; ++c) {
    Gsrc[c] = Wg + (size_t)e * FDIM * HDIM + (size_t)(n0 + c * 64 + w * 8 + sr) * HDIM + sc;
    Usrc[c] = Wu + (size_t)e * FDIM * HDIM + (size_t)(n0 + c * 64 + w * 8 + sr) * HDIM + sc;
  }
  f32x4 ag[4][4] = {}, au[4][4] = {};
  auto stgA = [&](int b, int kt) {  // 4 gload16: A rows 0..255
#pragma unroll
    for (int c = 0; c < 4; ++c) g2l16(Asrc[c] + kt, sm + b * 32768 + c * 4096 + w * 512);
  };
  auto stgGU = [&](int b, int kt) {  // 4 gload16: G rows 0..127, U rows 0..127
#pragma unroll
    for (int c = 0; c < 2; ++c) {
      g2l16(Gsrc[c] + kt, sm + b * 32768 + 16384 + c * 4096 + w * 512);
      g2l16(Usrc[c] + kt, sm + b * 32768 + 24576 + c * 4096 + w * 512);
    }
  };
  stgA(0, 0); stgGU(0, 0);
  WAITV0(); BAR(); SCB();
#pragma unroll 2
  for (int t = 0; t < 8; ++t) {
    const int bu = t & 1, bn = bu ^ 1;
    const u16* A_ = sm + bu * 32768;
    const u16* G_ = A_ + 16384;
    const u16* U_ = A_ + 24576;
    bf16x8 af[4], gf[4], uf[4];
    // phase 1: af+gf @kk0, issue next A, MFMA ag
#pragma unroll
    for (int i = 0; i < 4; ++i) af[i] = *(const bf16x8*)(A_ + (wr * 64 + i * 16 + lm) * 64 + ko0);
#pragma unroll
    for (int j = 0; j < 4; ++j) gf[j] = *(const bf16x8*)(G_ + (wc * 64 + j * 16 + lm) * 64 + ko0);
    if (t < 7) stgA(bn, (t + 1) * 64);
    PRIO1();
#pragma unroll
    for (int i = 0; i < 4; ++i)
#pragma unroll
      for (int j = 0; j < 4; ++j)
        ag[i][j] = __builtin_amdgcn_mfma_f32_16x16x32_bf16(af[i], gf[j], ag[i][j], 0, 0, 0);
    PRIO0();
    BAR(); SCB();
    // phase 2: uf @kk0, issue next G/U, MFMA au
#pragma unroll
    for (int j = 0; j < 4; ++j) uf[j] = *(const bf16x8*)(U_ + (wc * 64 + j * 16 + lm) * 64 + ko0);
    if (t < 7) stgGU(bn, (t + 1) * 64);
    PRIO1();
#pragma unroll
    for (int i = 0; i < 4; ++i)
#pragma unroll
      for (int j = 0; j < 4; ++j)
        au[i][j] = __builtin_amdgcn_mfma_f32_16x16x32_bf16(af[i], uf[j], au[i][j], 0, 0, 0);
    PRIO0();
    BAR(); SCB();
    // phase 3: af+gf @kk1, MFMA ag
#pragma unroll
    for (int i = 0; i < 4; ++i) af[i] = *(const bf16x8*)(A_ + (wr * 64 + i * 16 + lm) * 64 + ko1);
#pragma unroll
    for (int j = 0; j < 4; ++j) gf[j] = *(const bf16x8*)(G_ + (wc * 64 + j * 16 + lm) * 64 + ko1);
    PRIO1();
#pragma unroll
    for (int i = 0; i < 4; ++i)
#pragma unroll
      for (int j = 0; j < 4; ++j)
        ag[i][j] = __builtin_amdgcn_mfma_f32_16x16x32_bf16(af[i], gf[j], ag[i][j], 0, 0, 0);
    PRIO0();
    BAR(); SCB();
    // phase 4: uf @kk1, MFMA au, tile-boundary drain
#pragma unroll
    for (int j = 0; j < 4; ++j) uf[j] = *(const bf16x8*)(U_ + (wc * 64 + j * 16 + lm) * 64 + ko1);
    PRIO1();
#pragma unroll
    for (int i = 0; i < 4; ++i)
#pragma unroll
      for (int j = 0; j < 4; ++j)
        au[i][j] = __builtin_amdgcn_mfma_f32_16x16x32_bf16(af[i], uf[j], au[i][j], 0, 0, 0);
    PRIO0();
    if (t < 7) WAITV0();
    BAR(); SCB();
  }
  const int cr = (l >> 4) * 4, cc = lm;
#pragma unroll
  for (int i = 0; i < 4; ++i)
#pragma unroll
    for (int j = 0; j < 4; ++j)
#pragma unroll
      for (int r = 0; r < 4; ++r) {
        const float g = ag[i][j][r], u = au[i][j][r];
        const float s = g / (1.0f + __expf(-g));
        act[(size_t)(p0 + wr * 64 + i * 16 + cr + r) * FDIM + n0 + wc * 64 + j * 16 + cc] =
            f2bf(s * u);
      }
}

// ---- down: 128x128 tile, 4 waves of 64x64, BK=64 (32 tiles), 2-stage 64 KB -> 2 blk/CU,
// ---- 2 phases/K-tile, all stage-issues in P1, vmcnt(0) at tile end ----
__global__ __launch_bounds__(256, 2) void down_kernel(
    const u16* __restrict__ act, const u16* __restrict__ Wd, u16* __restrict__ dwn,
    const int* __restrict__ rbe1, const int* __restrict__ rbp1, const int* __restrict__ nrb) {
  const int rb = blockIdx.y;
  if (rb >= nrb[1]) return;
  __shared__ __align__(16) u16 sm[32768];  // 64 KB: 2 x (A[128][64] | B[128][64])
  const int e = rbe1[rb], p0 = rbp1[rb], n0 = blockIdx.x * 128;
  const int tid = threadIdx.x, w = tid >> 6, l = tid & 63;
  const int wr = w >> 1, wc = w & 1;
  const int lm = l & 15, lk = (l >> 4) * 8, xr = (l & 7) * 8;
  const int sr = l >> 3, sc = ((l & 7) ^ sr) * 8;
  const int ko0 = lk ^ xr, ko1 = (32 + lk) ^ xr;
  const u16 *Asrc[4], *Bsrc[4];
#pragma unroll
  for (int c = 0; c < 4; ++c) {
    Asrc[c] = act + (size_t)(p0 + c * 32 + w * 8 + sr) * FDIM + sc;
    Bsrc[c] = Wd + (size_t)e * HDIM * FDIM + (size_t)(n0 + c * 32 + w * 8 + sr) * FDIM + sc;
  }
  f32x4 acc[4][4] = {};
  auto STG = [&](int b, int kt) {  // 8 gload16
#pragma unroll
    for (int c = 0; c < 4; ++c) {
      g2l16(Asrc[c] + kt, sm + b * 16384 + c * 2048 + w * 512);
      g2l16(Bsrc[c] + kt, sm + b * 16384 + 8192 + c * 2048 + w * 512);
    }
  };
  STG(0, 0);
  WAITV0(); BAR(); SCB();
#pragma unroll 2
  for (int t = 0; t < 32; ++t) {
    const int bu = t & 1, bn = bu ^ 1;
    const u16* A_ = sm + bu * 16384;
    const u16* B_ = A_ + 8192;
    bf16x8 af[4], bf[4];
    // phase 1: kk0 + issue whole next tile
#pragma unroll
    for (int i = 0; i < 4; ++i) af[i] = *(const bf16x8*)(A_ + (wr * 64 + i * 16 + lm) * 64 + ko0);
#pragma unroll
    for (int j = 0; j < 4; ++j) bf[j] = *(const bf16x8*)(B_ + (wc * 64 + j * 16 + lm) * 64 + ko0);
    if (t < 31) STG(bn, (t + 1) * 64);
    PRIO1();
#pragma unroll
    for (int i = 0; i < 4; ++i)
#pragma unroll
      for (int j = 0; j < 4; ++j)
        acc[i][j] = __builtin_amdgcn_mfma_f32_16x16x32_bf16(af[i], bf[j], acc[i][j], 0, 0, 0);
    PRIO0();
    BAR(); SCB();
    // phase 2: kk1 + tile-boundary drain
#pragma unroll
    for (int i = 0; i < 4; ++i) af[i] = *(const bf16x8*)(A_ + (wr * 64 + i * 16 + lm) * 64 + ko1);
#pragma unroll
    for (int j = 0; j < 4; ++j) bf[j] = *(const bf16x8*)(B_ + (wc * 64 + j * 16 + lm) * 64 + ko1);
    PRIO1();
#pragma unroll
    for (int i = 0; i < 4; ++i)
#pragma unroll
      for (int j = 0; j < 4; ++j)
        acc[i][j] = __builtin_amdgcn_mfma_f32_16x16x32_bf16(af[i], bf[j], acc[i][j], 0, 0, 0);
    PRIO0();
    if (t < 31) WAITV0();
    BAR(); SCB();
  }
  const int cr = (l >> 4) * 4, cc = lm;
#pragma unroll
  for (int i = 0; i < 4; ++i)
#pragma unroll
    for (int j = 0; j < 4; ++j)
#pragma unroll
      for (int r = 0; r < 4; ++r)
        dwn[(size_t)(p0 + wr * 64 + i * 16 + cr + r) * HDIM + n0 + wc * 64 + j * 16 + cc] =
            f2bf(acc[i][j][r]);
}

// ---------------- combine: c[n] = w0*down[pos0] + w1*down[pos1] (bf16 in/out) ----------------
__global__ void combine_kernel(const u16* __restrict__ dwn, const int* __restrict__ pos,
                               const float* __restrict__ wts, u16* __restrict__ cb) {
  const int n = blockIdx.x, t = threadIdx.x;  // 128 threads x 4 elems
  const int p0 = pos[2 * n], p1 = pos[2 * n + 1];
  const float w0 = wts[2 * n], w1 = wts[2 * n + 1];
  const ushort4 a = ((const ushort4*)(dwn + (size_t)p0 * HDIM))[t];
  const ushort4 b = ((const ushort4*)(dwn + (size_t)p1 * HDIM))[t];
  ushort4 o;
  o.x = f2bf(w0 * bf2f(a.x) + w1 * bf2f(b.x));
  o.y = f2bf(w0 * bf2f(a.y) + w1 * bf2f(b.y));
  o.z = f2bf(w0 * bf2f(a.z) + w1 * bf2f(b.z));
  o.w = f2bf(w0 * bf2f(a.w) + w1 * bf2f(b.w));
  ((ushort4*)(cb + (size_t)n * HDIM))[t] = o;
}

extern "C" void kernel_launch(void* const* d_in, const int* in_sizes, int n_in,
                              void* d_out, int out_size, void* d_ws, size_t ws_size,
                              hipStream_t stream) {
  const float* x  = (const float*)d_in[0];
  const float* Wi = (const float*)d_in[1];
  const float* Wr = (const float*)d_in[2];
  const float* Wg = (const float*)d_in[3];
  const float* Wu = (const float*)d_in[4];
  const float* Wd = (const float*)d_in[5];
  const float* Wo = (const float*)d_in[6];
  float* out = (float*)d_out;

  char* ws = (char*)d_ws;
  size_t off = 0;
  auto alloc = [&](size_t bytes) -> void* {
    off = (off + 255) & ~(size_t)255;
    void* p = ws + off;
    off += bytes;
    return p;
  };
  u16* xb  = (u16*)alloc((size_t)NTOK * HDIM * 2);
  u16* hb  = (u16*)alloc((size_t)NTOK * HDIM * 2);
  u16* cb  = (u16*)alloc((size_t)NTOK * HDIM * 2);
  u16* Wib = (u16*)alloc((size_t)HDIM * HDIM * 2);
  u16* Wob = (u16*)alloc((size_t)HDIM * HDIM * 2);
  u16* Wgb = (u16*)alloc((size_t)NEXP * FDIM * HDIM * 2);
  u16* Wub = (u16*)alloc((size_t)NEXP * FDIM * HDIM * 2);
  u16* Wdb = (u16*)alloc((size_t)NEXP * HDIM * FDIM * 2);
  u16* actb = (u16*)alloc((size_t)NPAD2 * FDIM * 2);
  u16* dwn = (u16*)alloc((size_t)NPAD2 * HDIM * 2);
  double* wre = (double*)alloc((size_t)NEXP * HDIM * 8);
  int* idx = (int*)alloc((size_t)NASSIGN * 4);
  float* wts = (float*)alloc((size_t)NASSIGN * 4);
  int* tok = (int*)alloc((size_t)NPAD2 * 4);
  int* pos = (int*)alloc((size_t)NASSIGN * 4);
  int* rbe2 = (int*)alloc((size_t)RBMAX * 4);
  int* rbp2 = (int*)alloc((size_t)RBMAX * 4);
  int* rbe1 = (int*)alloc((size_t)RBMAX * 4);
  int* rbp1 = (int*)alloc((size_t)RBMAX * 4);
  int* nrb = (int*)alloc(256);

  cvtall_kernel<<<6800, 256, 0, stream>>>(x, Wi, Wo, Wg, Wu, Wd, Wr,
                                          xb, Wib, Wob, Wgb, Wub, Wdb, wre);
  router_kernel<<<32, 128, 0, stream>>>(x, wre, idx, wts);
  assign_kernel<<<1, 256, 0, stream>>>(idx, tok, pos, rbe2, rbp2, rbe1, rbp1, nrb);
  ingemm_kernel<<<dim3(4, 32), 512, 0, stream>>>(xb, Wib, hb);
  gateup_kernel<<<dim3(16, 40), 512, 0, stream>>>(hb, Wgb, Wub, actb, tok, rbe2, rbp2, nrb);
  down_kernel<<<dim3(4, 72), 256, 0, stream>>>(actb, Wdb, dwn, rbe1, rbp1, nrb);
  combine_kernel<<<NTOK, 128, 0, stream>>>(dwn, pos, wts, cb);
  outgemm_kernel<<<dim3(4, 32), 512, 0, stream>>>(cb, Wob, out);
}